// Round 9
// baseline (223.316 us; speedup 1.0000x reference)
//
#include <hip/hip_runtime.h>

// MaskAttention: B=4, C=128, H=W=64 -> N=4096
// Round 9 (= round 7 + working compile): 2 independent blocks/CU. attn: TQ=32,
// grid 512, 4 waves = kj slices of 16 keys; swapped QK^T C-layout == 16x16x16
// B-layout -> P stays in registers (no P LDS). 4-way kj merge + fused LN.

#define CCH 128
#define NTOK 4096

typedef __attribute__((ext_vector_type(8))) short  bf16x8;
typedef __attribute__((ext_vector_type(4))) short  bf16x4;
typedef __attribute__((ext_vector_type(4))) float  f32x4;

// NOTE: amdgcn MFMA builtins parse in BOTH hipcc passes (host pass included) —
// call them directly; do NOT guard with __has_builtin (false in host pass) or
// host stubs (host overload not viable inside __global__). Lesson of r7/r8.
__device__ __forceinline__ f32x4 mfma16(bf16x4 a, bf16x4 b, f32x4 c) {
    return __builtin_amdgcn_mfma_f32_16x16x16bf16_1k(a, b, c, 0, 0, 0);
}

__device__ __forceinline__ unsigned short f2bf(float f) {
    unsigned int u = __builtin_bit_cast(unsigned int, f);
    u += 0x7FFFu + ((u >> 16) & 1u);      // RNE (finite inputs)
    return (unsigned short)(u >> 16);
}
__device__ __forceinline__ unsigned int pack2bf(float a, float b) {
    return (unsigned int)f2bf(a) | ((unsigned int)f2bf(b) << 16);
}
__device__ __forceinline__ void gload_lds16(const void* g, void* l) {
    __builtin_amdgcn_global_load_lds(
        (const __attribute__((address_space(1))) unsigned int*)g,
        (__attribute__((address_space(3))) unsigned int*)l, 16, 0, 0);
}

// ---------------- k1: QKV projections via MFMA (round-5, unchanged) ----------------
__device__ __forceinline__ void stageW(char* Wb, const float* __restrict__ W, int t) {
    const int co = t >> 1, h = t & 1;
    const float4* src = reinterpret_cast<const float4*>(W + co * CCH + h * 64);
    char* row = Wb + co * 256;
    const int sw = (co & 7) << 3;
    #pragma unroll
    for (int q = 0; q < 16; ++q) {
        const float4 v = src[q];
        const int c2 = h * 32 + q * 2;
        *reinterpret_cast<unsigned int*>(row + (((c2    ) ^ sw) << 2)) = pack2bf(v.x, v.y);
        *reinterpret_cast<unsigned int*>(row + (((c2 + 1) ^ sw) << 2)) = pack2bf(v.z, v.w);
    }
}

__global__ __launch_bounds__(256) void qkv_kernel(
    const float* __restrict__ prompt, const float* __restrict__ xg,
    const float* __restrict__ Wq, const float* __restrict__ bq,
    const float* __restrict__ Wk, const float* __restrict__ bk,
    const float* __restrict__ Wv, const float* __restrict__ bv,
    unsigned short* __restrict__ Qo, unsigned short* __restrict__ Ko,
    unsigned short* __restrict__ Vo)
{
    extern __shared__ __align__(16) char qpool[];
    char* pT = qpool;
    char* xT = qpool + 16384;
    char* Wb = qpool + 32768;

    const int t  = threadIdx.x;
    const int b  = blockIdx.x >> 6;
    const int n0 = (blockIdx.x & 63) << 6;
    const int l  = t & 63;
    const int w  = t >> 6;
    const int g  = l >> 4;
    const int lr = l & 15;

    {
        const int c2 = t & 63, th = t >> 6;
        const float* ps = prompt + (((size_t)b * CCH + 2 * c2) << 12) + n0 + th * 16;
        const float* xs = xg     + (((size_t)b * CCH + 2 * c2) << 12) + n0 + th * 16;
        float pa[16], pb[16], xa[16], xb[16];
        #pragma unroll
        for (int q = 0; q < 4; ++q) {
            *reinterpret_cast<float4*>(&pa[q*4]) = *reinterpret_cast<const float4*>(ps + q*4);
            *reinterpret_cast<float4*>(&pb[q*4]) = *reinterpret_cast<const float4*>(ps + 4096 + q*4);
            *reinterpret_cast<float4*>(&xa[q*4]) = *reinterpret_cast<const float4*>(xs + q*4);
            *reinterpret_cast<float4*>(&xb[q*4]) = *reinterpret_cast<const float4*>(xs + 4096 + q*4);
        }
        #pragma unroll
        for (int j = 0; j < 16; ++j) {
            const int tok = th * 16 + j;
            const int off = tok * 256 + (((c2) ^ ((tok & 7) << 3)) << 2);
            *reinterpret_cast<unsigned int*>(pT + off) = pack2bf(pa[j], pb[j]);
            *reinterpret_cast<unsigned int*>(xT + off) = pack2bf(xa[j], xb[j]);
        }
    }
    stageW(Wb, Wq, t);
    __syncthreads();

    const float SC2 = 0.12754849f;   // log2(e)/sqrt(128)
    const int swl = (lr & 7) << 3;

    {   // phase Q
        bf16x8 af[4];
        #pragma unroll
        for (int s = 0; s < 4; ++s)
            af[s] = *reinterpret_cast<const bf16x8*>(
                pT + (w * 16 + lr) * 256 + (((s * 16 + g * 4) ^ swl) << 2));
        f32x4 acc[8];
        #pragma unroll
        for (int cf = 0; cf < 8; ++cf) acc[cf] = (f32x4){0.f,0.f,0.f,0.f};
        #pragma unroll
        for (int cf = 0; cf < 8; ++cf)
            #pragma unroll
            for (int s = 0; s < 4; ++s) {
                bf16x8 bf = *reinterpret_cast<const bf16x8*>(
                    Wb + (cf * 16 + lr) * 256 + (((s * 16 + g * 4) ^ swl) << 2));
                acc[cf] = __builtin_amdgcn_mfma_f32_16x16x32_bf16(af[s], bf, acc[cf], 0, 0, 0);
            }
        #pragma unroll
        for (int cf = 0; cf < 8; ++cf) {
            const float bb = bq[cf * 16 + lr];
            #pragma unroll
            for (int i = 0; i < 4; ++i) {
                const int tok = w * 16 + g * 4 + i;
                Qo[((size_t)(b * NTOK + n0 + tok) << 7) + cf * 16 + lr] =
                    f2bf((acc[cf][i] + bb) * SC2);
            }
        }
    }
    __syncthreads();
    stageW(Wb, Wk, t);
    __syncthreads();

    bf16x8 af[4];
    #pragma unroll
    for (int s = 0; s < 4; ++s)
        af[s] = *reinterpret_cast<const bf16x8*>(
            xT + (w * 16 + lr) * 256 + (((s * 16 + g * 4) ^ swl) << 2));
    {   // phase K
        f32x4 acc[8];
        #pragma unroll
        for (int cf = 0; cf < 8; ++cf) acc[cf] = (f32x4){0.f,0.f,0.f,0.f};
        #pragma unroll
        for (int cf = 0; cf < 8; ++cf)
            #pragma unroll
            for (int s = 0; s < 4; ++s) {
                bf16x8 bf = *reinterpret_cast<const bf16x8*>(
                    Wb + (cf * 16 + lr) * 256 + (((s * 16 + g * 4) ^ swl) << 2));
                acc[cf] = __builtin_amdgcn_mfma_f32_16x16x32_bf16(af[s], bf, acc[cf], 0, 0, 0);
            }
        #pragma unroll
        for (int cf = 0; cf < 8; ++cf) {
            const float bb = bk[cf * 16 + lr];
            #pragma unroll
            for (int i = 0; i < 4; ++i) {
                const int tok = w * 16 + g * 4 + i;
                Ko[((size_t)(b * NTOK + n0 + tok) << 7) + cf * 16 + lr] =
                    f2bf(acc[cf][i] + bb);
            }
        }
    }
    __syncthreads();
    stageW(Wb, Wv, t);
    __syncthreads();

    {   // phase V (transposed store)
        f32x4 acc[8];
        #pragma unroll
        for (int cf = 0; cf < 8; ++cf) acc[cf] = (f32x4){0.f,0.f,0.f,0.f};
        #pragma unroll
        for (int cf = 0; cf < 8; ++cf)
            #pragma unroll
            for (int s = 0; s < 4; ++s) {
                bf16x8 bf = *reinterpret_cast<const bf16x8*>(
                    Wb + (cf * 16 + lr) * 256 + (((s * 16 + g * 4) ^ swl) << 2));
                acc[cf] = __builtin_amdgcn_mfma_f32_16x16x32_bf16(af[s], bf, acc[cf], 0, 0, 0);
            }
        #pragma unroll
        for (int cf = 0; cf < 8; ++cf) {
            const float bb = bv[cf * 16 + lr];
            unsigned short pk[4];
            #pragma unroll
            for (int i = 0; i < 4; ++i) pk[i] = f2bf(acc[cf][i] + bb);
            *reinterpret_cast<unsigned long long*>(
                Vo + (((size_t)(b * CCH + cf * 16 + lr)) << 12) + n0 + w * 16 + g * 4) =
                *reinterpret_cast<unsigned long long*>(pk);
        }
    }
}

// ---------------- k2: attention ----------------
// TQ=32, grid 512 (2 blocks/CU), 256 thr = 4 waves (kj = 16-key slice of each
// 64-key tile). Dynamic LDS 71680:
//   K dbuf @0      2 x 16384  (64 rows x 256B, 16B-chunk ^ (row&7))
//   V dbuf @32768  2 x 16384  (128 ch rows x 128B, same swizzle)
//   epilogue reuse: mrg @0 (3 x 64 x 69 f32), xstg @53248 (128 x 36 f32)
__device__ __forceinline__ void stage_tile(
    const unsigned short* __restrict__ Kg, const unsigned short* __restrict__ Vg,
    char* KsB, char* VsB, int b, int m0, int w4, int l)
{
    #pragma unroll
    for (int ii = 0; ii < 4; ++ii) {        // K: 4 x 1KB chunks (4 rows each)
        const int i = w4 * 4 + ii;
        const int r = i * 4 + (l >> 4);
        const int csrc = (l & 15) ^ (r & 7);
        const unsigned short* src = Kg + ((size_t)(b * NTOK + m0 + r) << 7) + csrc * 8;
        gload_lds16(src, KsB + i * 1024);
    }
    #pragma unroll
    for (int ii = 0; ii < 4; ++ii) {        // V: 4 x 1KB chunks (8 rows each)
        const int i = w4 * 4 + ii;
        const int r = i * 8 + (l >> 3);
        const int csrc = (l & 7) ^ (r & 7);
        const unsigned short* src = Vg + ((size_t)(b * CCH + r) << 12) + m0 + csrc * 8;
        gload_lds16(src, VsB + i * 1024);
    }
}

__global__ __launch_bounds__(256) void attn_ln_kernel(
    const unsigned short* __restrict__ Qg, const unsigned short* __restrict__ Kg,
    const unsigned short* __restrict__ Vg,
    const int* __restrict__ maskb, const float* __restrict__ xg,
    const float* __restrict__ gamma, const float* __restrict__ beta,
    float* __restrict__ out)
{
    extern __shared__ __align__(16) char pool[];
    char* KsBuf = pool;
    char* VsBuf = pool + 32768;
    float* mrg  = (float*)pool;
    float* xstg = (float*)(pool + 53248);

    // XCD swizzle over 512 blocks: batch b -> 2 XCDs (K+V 2MB in 8MB L2)
    const int raw = blockIdx.x;
    const int bid = (raw & 7) * 64 + (raw >> 3);
    const int t  = threadIdx.x;
    const int b  = bid >> 7;
    const int n0 = (bid & 127) << 5;
    const int l  = t & 63;
    const int kj = t >> 6;        // 16-key slice id
    const int g  = l >> 4;
    const int lr = l & 15;
    const int swz = (lr & 7) << 4;

    // Q fragments (B-operand): lane holds Q[n0+rf*16+lr][s*32 + g*8 + j]
    bf16x8 qf[2][4];
    #pragma unroll
    for (int rf = 0; rf < 2; ++rf) {
        const unsigned short* qp =
            Qg + ((size_t)(b * NTOK + n0 + rf * 16 + lr)) * CCH + g * 8;
        #pragma unroll
        for (int s = 0; s < 4; ++s)
            qf[rf][s] = *reinterpret_cast<const bf16x8*>(qp + s * 32);
    }

    // acc[rf][cf][i] = O^T[ch = cf*16+g*4+i][q = rf*16+lr]
    f32x4 acc[2][8];
    float mrun[2], lrun[2];
    #pragma unroll
    for (int rf = 0; rf < 2; ++rf) {
        #pragma unroll
        for (int cf = 0; cf < 8; ++cf) acc[rf][cf] = (f32x4){0.f,0.f,0.f,0.f};
        mrun[rf] = -1e30f; lrun[rf] = 0.f;
    }

    stage_tile(Kg, Vg, KsBuf, VsBuf, b, 0, kj, l);

    for (int kt = 0; kt < 64; ++kt) {
        __builtin_amdgcn_s_barrier();            // [A] prev reads done
        __builtin_amdgcn_sched_barrier(0);

        const int m0 = kt << 6;
        const int4 mv = *reinterpret_cast<const int4*>(
            maskb + (size_t)b * NTOK + m0 + kj * 16 + g * 4);

        const int tn = (kt + 1) & 63;            // wrap-stage keeps vmcnt math exact
        stage_tile(Kg, Vg, KsBuf + (tn & 1) * 16384, VsBuf + (tn & 1) * 16384,
                   b, tn << 6, kj, l);

        asm volatile("s_waitcnt vmcnt(9)" ::: "memory");  // stage(kt) drained
        __builtin_amdgcn_sched_barrier(0);
        __builtin_amdgcn_s_barrier();            // [B] stage(kt) visible
        __builtin_amdgcn_sched_barrier(0);

        const char* Ks_c = KsBuf + (kt & 1) * 16384;
        const char* Vs_c = VsBuf + (kt & 1) * 16384;

        // ---- S^T = mfma(K, Q): lane holds S[key=kj*16+g*4+i][q=rf*16+lr] ----
        f32x4 sf[2];
        sf[0] = (f32x4){0.f,0.f,0.f,0.f};
        sf[1] = (f32x4){0.f,0.f,0.f,0.f};
        {
            const char* rp = Ks_c + (kj * 16 + lr) * 256;
            #pragma unroll
            for (int s = 0; s < 4; ++s) {
                bf16x8 kb = *reinterpret_cast<const bf16x8*>(rp + ((s * 64 + g * 16) ^ swz));
                sf[0] = __builtin_amdgcn_mfma_f32_16x16x32_bf16(kb, qf[0][s], sf[0], 0, 0, 0);
                sf[1] = __builtin_amdgcn_mfma_f32_16x16x32_bf16(kb, qf[1][s], sf[1], 0, 0, 0);
            }
        }

        const float mk[4] = { mv.x ? 1.f : 0.f, mv.y ? 1.f : 0.f,
                              mv.z ? 1.f : 0.f, mv.w ? 1.f : 0.f };

        // ---- softmax + P in registers (S^T C-layout == 16x16x16 B-layout) ----
        bf16x4 pb[2];
        #pragma unroll
        for (int rf = 0; rf < 2; ++rf) {
            float rm = fmaxf(fmaxf(sf[rf][0], sf[rf][1]), fmaxf(sf[rf][2], sf[rf][3]));
            rm = fmaxf(rm, __shfl_xor(rm, 16));
            rm = fmaxf(rm, __shfl_xor(rm, 32));
            if (!__all(rm <= mrun[rf])) {        // exact skip: cr==1 when skipped
                const float mn = fmaxf(mrun[rf], rm);
                const float cr = exp2f(mrun[rf] - mn);
                mrun[rf] = mn;
                lrun[rf] *= cr;
                #pragma unroll
                for (int cf = 0; cf < 8; ++cf) {
                    acc[rf][cf][0] *= cr; acc[rf][cf][1] *= cr;
                    acc[rf][cf][2] *= cr; acc[rf][cf][3] *= cr;
                }
            }
            const float p0 = exp2f(sf[rf][0] - mrun[rf]) * mk[0];
            const float p1 = exp2f(sf[rf][1] - mrun[rf]) * mk[1];
            const float p2 = exp2f(sf[rf][2] - mrun[rf]) * mk[2];
            const float p3 = exp2f(sf[rf][3] - mrun[rf]) * mk[3];
            lrun[rf] += (p0 + p1) + (p2 + p3);   // per-lane partial (4 keys)
            const unsigned long long pk =
                (unsigned long long)pack2bf(p0, p1) |
                ((unsigned long long)pack2bf(p2, p3) << 32);
            pb[rf] = __builtin_bit_cast(bf16x4, pk);
        }

        // ---- O^T += mfma16(V, P): V b64 from LDS, P from registers ----
        #pragma unroll
        for (int cf = 0; cf < 8; ++cf) {
            const bf16x4 vb = *reinterpret_cast<const bf16x4*>(
                Vs_c + (cf * 16 + lr) * 128 +
                ((((kj * 2 + (g >> 1)) ^ (lr & 7)) << 4) + ((g & 1) << 3)));
            acc[0][cf] = mfma16(vb, pb[0], acc[0][cf]);
            acc[1][cf] = mfma16(vb, pb[1], acc[1][cf]);
        }
    }

    // ---------------- 4-way kj merge + residual + LayerNorm + transpose ----------------
    asm volatile("s_waitcnt vmcnt(0)" ::: "memory");   // dangling wrap-stage done
    #pragma unroll
    for (int rf = 0; rf < 2; ++rf) {     // finish deferred row sums across g
        lrun[rf] += __shfl_xor(lrun[rf], 16);
        lrun[rf] += __shfl_xor(lrun[rf], 32);
    }
    __syncthreads();

    if (kj != 0) {                       // publish partials, stride 69 floats
        float* dst = mrg + ((kj - 1) * 64 + l) * 69;
        #pragma unroll
        for (int rf = 0; rf < 2; ++rf)
            #pragma unroll
            for (int cf = 0; cf < 8; ++cf)
                #pragma unroll
                for (int i = 0; i < 4; ++i)
                    dst[rf * 32 + cf * 4 + i] = acc[rf][cf][i];
        dst[64] = mrun[0]; dst[65] = mrun[1];
        dst[66] = lrun[0]; dst[67] = lrun[1];
    }
    {   // stage x tile (c-major, stride 36)
        const int c = t >> 1, h0 = (t & 1) << 4;
        const float* src = xg + (((size_t)b * CCH + c) << 12) + n0 + h0;
        float* dst = xstg + c * 36 + h0;
        #pragma unroll
        for (int k = 0; k < 16; k += 4)
            *reinterpret_cast<float4*>(dst + k) = *reinterpret_cast<const float4*>(src + k);
    }
    __syncthreads();

    if (kj == 0) {
        const float* r1 = mrg + (0 * 64 + l) * 69;
        const float* r2 = mrg + (1 * 64 + l) * 69;
        const float* r3 = mrg + (2 * 64 + l) * 69;
        float gm[8][4], bt[8][4];
        #pragma unroll
        for (int cf = 0; cf < 8; ++cf)
            #pragma unroll
            for (int i = 0; i < 4; ++i) {
                gm[cf][i] = gamma[cf * 16 + g * 4 + i];
                bt[cf][i] = beta [cf * 16 + g * 4 + i];
            }
        #pragma unroll
        for (int rf = 0; rf < 2; ++rf) {
            const float mA = r1[64 + rf], mB = r2[64 + rf], mC = r3[64 + rf];
            const float lA = r1[66 + rf], lB = r2[66 + rf], lC = r3[66 + rf];
            const float mx = fmaxf(fmaxf(mrun[rf], mA), fmaxf(mB, mC));
            const float e0 = exp2f(mrun[rf] - mx);
            const float eA = exp2f(mA - mx);
            const float eB = exp2f(mB - mx);
            const float eC = exp2f(mC - mx);
            const float inv = 1.f / (lrun[rf] * e0 + lA * eA + lB * eB + lC * eC);
            const int nloc = rf * 16 + lr;
            float sum = 0.f, sq = 0.f;
            #pragma unroll
            for (int cf = 0; cf < 8; ++cf)
                #pragma unroll
                for (int i = 0; i < 4; ++i) {
                    const int idx = rf * 32 + cf * 4 + i;
                    const float o = acc[rf][cf][i] * e0 + r1[idx] * eA
                                  + r2[idx] * eB + r3[idx] * eC;
                    const float v = o * inv + xstg[(cf * 16 + g * 4 + i) * 36 + nloc];
                    acc[rf][cf][i] = v; sum += v; sq += v * v;
                }
            sum += __shfl_xor(sum, 16); sq += __shfl_xor(sq, 16);
            sum += __shfl_xor(sum, 32); sq += __shfl_xor(sq, 32);
            const float mean = sum * (1.f / 128.f);
            const float var  = sq * (1.f / 128.f) - mean * mean;
            const float rstd = rsqrtf(var + 1e-5f);
            #pragma unroll
            for (int cf = 0; cf < 8; ++cf)
                #pragma unroll
                for (int i = 0; i < 4; ++i)
                    xstg[(cf * 16 + g * 4 + i) * 36 + nloc] =
                        (acc[rf][cf][i] - mean) * rstd * gm[cf][i] + bt[cf][i];
        }
    }
    __syncthreads();

    {   // coalesced transposed store
        const int c = t >> 1, h0 = (t & 1) << 4;
        float* dst = out + (((size_t)b * CCH + c) << 12) + n0 + h0;
        const float* srcl = xstg + c * 36 + h0;
        #pragma unroll
        for (int k = 0; k < 16; k += 4)
            *reinterpret_cast<float4*>(dst + k) = *reinterpret_cast<const float4*>(srcl + k);
    }
}

extern "C" void kernel_launch(void* const* d_in, const int* in_sizes, int n_in,
                              void* d_out, int out_size, void* d_ws, size_t ws_size,
                              hipStream_t stream) {
    const float* prompt = (const float*)d_in[0];
    const float* x      = (const float*)d_in[1];
    const float* Wq     = (const float*)d_in[2];
    const float* bq     = (const float*)d_in[3];
    const float* Wk     = (const float*)d_in[4];
    const float* bk     = (const float*)d_in[5];
    const float* Wv     = (const float*)d_in[6];
    const float* bv     = (const float*)d_in[7];
    const float* gamma  = (const float*)d_in[8];
    const float* beta   = (const float*)d_in[9];
    const int*   maskb  = (const int*)d_in[10];
    float* out = (float*)d_out;

    const size_t M = (size_t)4 * NTOK * CCH;
    unsigned short* Qw = (unsigned short*)d_ws;
    unsigned short* Kw = Qw + M;
    unsigned short* Vw = Kw + M;

    (void)hipFuncSetAttribute((const void*)qkv_kernel,
                              hipFuncAttributeMaxDynamicSharedMemorySize, 65536);
    (void)hipFuncSetAttribute((const void*)attn_ln_kernel,
                              hipFuncAttributeMaxDynamicSharedMemorySize, 71680);

    qkv_kernel<<<256, 256, 65536, stream>>>(prompt, x, Wq, bq, Wk, bk, Wv, bv, Qw, Kw, Vw);
    attn_ln_kernel<<<512, 256, 71680, stream>>>(Qw, Kw, Vw, maskb, x, gamma, beta, out);
}

// Round 10
// 205.644 us; speedup vs baseline: 1.0859x; 1.0859x over previous
//
#include <hip/hip_runtime.h>

// MaskAttention: B=4, C=128, H=W=64 -> N=4096
// Round 10: barrier-free attention main loop. All MFMA fragments loaded DIRECTLY
// from global (L2-resident K/V): K-as-A (4x16B/lane), V-as-A 16x16x16 (8x8B/lane),
// Q & P in registers. No LDS, no barriers in the loop -> 8 independent wave
// streams/CU (2 blocks x 4 waves, 54KB static LDS used only by the epilogue).
// Wave kj owns keys [kj*1024,(kj+1)*1024); 4-way tree merge + fused residual+LN.

#define CCH 128
#define NTOK 4096

typedef __attribute__((ext_vector_type(8))) short  bf16x8;
typedef __attribute__((ext_vector_type(4))) short  bf16x4;
typedef __attribute__((ext_vector_type(4))) float  f32x4;

__device__ __forceinline__ f32x4 mfma16(bf16x4 a, bf16x4 b, f32x4 c) {
    return __builtin_amdgcn_mfma_f32_16x16x16bf16_1k(a, b, c, 0, 0, 0);
}

__device__ __forceinline__ unsigned short f2bf(float f) {
    unsigned int u = __builtin_bit_cast(unsigned int, f);
    u += 0x7FFFu + ((u >> 16) & 1u);      // RNE (finite inputs)
    return (unsigned short)(u >> 16);
}
__device__ __forceinline__ unsigned int pack2bf(float a, float b) {
    return (unsigned int)f2bf(a) | ((unsigned int)f2bf(b) << 16);
}

// ---------------- k1: QKV projections via MFMA (round-5, unchanged) ----------------
__device__ __forceinline__ void stageW(char* Wb, const float* __restrict__ W, int t) {
    const int co = t >> 1, h = t & 1;
    const float4* src = reinterpret_cast<const float4*>(W + co * CCH + h * 64);
    char* row = Wb + co * 256;
    const int sw = (co & 7) << 3;
    #pragma unroll
    for (int q = 0; q < 16; ++q) {
        const float4 v = src[q];
        const int c2 = h * 32 + q * 2;
        *reinterpret_cast<unsigned int*>(row + (((c2    ) ^ sw) << 2)) = pack2bf(v.x, v.y);
        *reinterpret_cast<unsigned int*>(row + (((c2 + 1) ^ sw) << 2)) = pack2bf(v.z, v.w);
    }
}

__global__ __launch_bounds__(256) void qkv_kernel(
    const float* __restrict__ prompt, const float* __restrict__ xg,
    const float* __restrict__ Wq, const float* __restrict__ bq,
    const float* __restrict__ Wk, const float* __restrict__ bk,
    const float* __restrict__ Wv, const float* __restrict__ bv,
    unsigned short* __restrict__ Qo, unsigned short* __restrict__ Ko,
    unsigned short* __restrict__ Vo)
{
    extern __shared__ __align__(16) char qpool[];
    char* pT = qpool;
    char* xT = qpool + 16384;
    char* Wb = qpool + 32768;

    const int t  = threadIdx.x;
    const int b  = blockIdx.x >> 6;
    const int n0 = (blockIdx.x & 63) << 6;
    const int l  = t & 63;
    const int w  = t >> 6;
    const int g  = l >> 4;
    const int lr = l & 15;

    {
        const int c2 = t & 63, th = t >> 6;
        const float* ps = prompt + (((size_t)b * CCH + 2 * c2) << 12) + n0 + th * 16;
        const float* xs = xg     + (((size_t)b * CCH + 2 * c2) << 12) + n0 + th * 16;
        float pa[16], pb[16], xa[16], xb[16];
        #pragma unroll
        for (int q = 0; q < 4; ++q) {
            *reinterpret_cast<float4*>(&pa[q*4]) = *reinterpret_cast<const float4*>(ps + q*4);
            *reinterpret_cast<float4*>(&pb[q*4]) = *reinterpret_cast<const float4*>(ps + 4096 + q*4);
            *reinterpret_cast<float4*>(&xa[q*4]) = *reinterpret_cast<const float4*>(xs + q*4);
            *reinterpret_cast<float4*>(&xb[q*4]) = *reinterpret_cast<const float4*>(xs + 4096 + q*4);
        }
        #pragma unroll
        for (int j = 0; j < 16; ++j) {
            const int tok = th * 16 + j;
            const int off = tok * 256 + (((c2) ^ ((tok & 7) << 3)) << 2);
            *reinterpret_cast<unsigned int*>(pT + off) = pack2bf(pa[j], pb[j]);
            *reinterpret_cast<unsigned int*>(xT + off) = pack2bf(xa[j], xb[j]);
        }
    }
    stageW(Wb, Wq, t);
    __syncthreads();

    const float SC2 = 0.12754849f;   // log2(e)/sqrt(128)
    const int swl = (lr & 7) << 3;

    {   // phase Q
        bf16x8 af[4];
        #pragma unroll
        for (int s = 0; s < 4; ++s)
            af[s] = *reinterpret_cast<const bf16x8*>(
                pT + (w * 16 + lr) * 256 + (((s * 16 + g * 4) ^ swl) << 2));
        f32x4 acc[8];
        #pragma unroll
        for (int cf = 0; cf < 8; ++cf) acc[cf] = (f32x4){0.f,0.f,0.f,0.f};
        #pragma unroll
        for (int cf = 0; cf < 8; ++cf)
            #pragma unroll
            for (int s = 0; s < 4; ++s) {
                bf16x8 bf = *reinterpret_cast<const bf16x8*>(
                    Wb + (cf * 16 + lr) * 256 + (((s * 16 + g * 4) ^ swl) << 2));
                acc[cf] = __builtin_amdgcn_mfma_f32_16x16x32_bf16(af[s], bf, acc[cf], 0, 0, 0);
            }
        #pragma unroll
        for (int cf = 0; cf < 8; ++cf) {
            const float bb = bq[cf * 16 + lr];
            #pragma unroll
            for (int i = 0; i < 4; ++i) {
                const int tok = w * 16 + g * 4 + i;
                Qo[((size_t)(b * NTOK + n0 + tok) << 7) + cf * 16 + lr] =
                    f2bf((acc[cf][i] + bb) * SC2);
            }
        }
    }
    __syncthreads();
    stageW(Wb, Wk, t);
    __syncthreads();

    bf16x8 af[4];
    #pragma unroll
    for (int s = 0; s < 4; ++s)
        af[s] = *reinterpret_cast<const bf16x8*>(
            xT + (w * 16 + lr) * 256 + (((s * 16 + g * 4) ^ swl) << 2));
    {   // phase K
        f32x4 acc[8];
        #pragma unroll
        for (int cf = 0; cf < 8; ++cf) acc[cf] = (f32x4){0.f,0.f,0.f,0.f};
        #pragma unroll
        for (int cf = 0; cf < 8; ++cf)
            #pragma unroll
            for (int s = 0; s < 4; ++s) {
                bf16x8 bf = *reinterpret_cast<const bf16x8*>(
                    Wb + (cf * 16 + lr) * 256 + (((s * 16 + g * 4) ^ swl) << 2));
                acc[cf] = __builtin_amdgcn_mfma_f32_16x16x32_bf16(af[s], bf, acc[cf], 0, 0, 0);
            }
        #pragma unroll
        for (int cf = 0; cf < 8; ++cf) {
            const float bb = bk[cf * 16 + lr];
            #pragma unroll
            for (int i = 0; i < 4; ++i) {
                const int tok = w * 16 + g * 4 + i;
                Ko[((size_t)(b * NTOK + n0 + tok) << 7) + cf * 16 + lr] =
                    f2bf(acc[cf][i] + bb);
            }
        }
    }
    __syncthreads();
    stageW(Wb, Wv, t);
    __syncthreads();

    {   // phase V (transposed store)
        f32x4 acc[8];
        #pragma unroll
        for (int cf = 0; cf < 8; ++cf) acc[cf] = (f32x4){0.f,0.f,0.f,0.f};
        #pragma unroll
        for (int cf = 0; cf < 8; ++cf)
            #pragma unroll
            for (int s = 0; s < 4; ++s) {
                bf16x8 bf = *reinterpret_cast<const bf16x8*>(
                    Wb + (cf * 16 + lr) * 256 + (((s * 16 + g * 4) ^ swl) << 2));
                acc[cf] = __builtin_amdgcn_mfma_f32_16x16x32_bf16(af[s], bf, acc[cf], 0, 0, 0);
            }
        #pragma unroll
        for (int cf = 0; cf < 8; ++cf) {
            const float bb = bv[cf * 16 + lr];
            unsigned short pk[4];
            #pragma unroll
            for (int i = 0; i < 4; ++i) pk[i] = f2bf(acc[cf][i] + bb);
            *reinterpret_cast<unsigned long long*>(
                Vo + (((size_t)(b * CCH + cf * 16 + lr)) << 12) + n0 + w * 16 + g * 4) =
                *reinterpret_cast<unsigned long long*>(pk);
        }
    }
}

// ---------------- k2: attention, barrier-free main loop ----------------
// grid 512 (2 blocks/CU), 256 thr = 4 waves. Wave kj: keys [kj*1024,(kj+1)*1024),
// 64 iters x 16 keys, all operands direct-from-global. Static LDS 55296B
// (epilogue only): mrg 2 slots x 64 x 69 f32 @0; xstg 128 x 36 f32 @36864.
__global__ __launch_bounds__(256, 2) void attn_ln_kernel(
    const unsigned short* __restrict__ Qg, const unsigned short* __restrict__ Kg,
    const unsigned short* __restrict__ Vg,
    const int* __restrict__ maskb, const float* __restrict__ xg,
    const float* __restrict__ gamma, const float* __restrict__ beta,
    float* __restrict__ out)
{
    __shared__ __align__(16) char pool[55296];
    float* mrg  = (float*)pool;
    float* xstg = (float*)(pool + 36864);

    // XCD swizzle: batch -> 2 XCDs so its K+V (2MB) lives in 2x4MB L2.
    const int raw = blockIdx.x;
    const int bid = (raw & 7) * 64 + (raw >> 3);
    const int t  = threadIdx.x;
    const int b  = bid >> 7;
    const int n0 = (bid & 127) << 5;
    const int l  = t & 63;
    const int kj = t >> 6;        // key-range quarter
    const int g  = l >> 4;
    const int lr = l & 15;

    // Q fragments (B-operand): lane holds Q[n0+rf*16+lr][s*32 + g*8 + j]
    bf16x8 qf[2][4];
    #pragma unroll
    for (int rf = 0; rf < 2; ++rf) {
        const unsigned short* qp =
            Qg + ((size_t)(b * NTOK + n0 + rf * 16 + lr)) * CCH + g * 8;
        #pragma unroll
        for (int s = 0; s < 4; ++s)
            qf[rf][s] = *reinterpret_cast<const bf16x8*>(qp + s * 32);
    }

    // acc[rf][cf][i] = O^T[ch = cf*16+g*4+i][q = rf*16+lr]
    f32x4 acc[2][8];
    float mrun[2], lrun[2];
    #pragma unroll
    for (int rf = 0; rf < 2; ++rf) {
        #pragma unroll
        for (int cf = 0; cf < 8; ++cf) acc[rf][cf] = (f32x4){0.f,0.f,0.f,0.f};
        mrun[rf] = -1e30f; lrun[rf] = 0.f;
    }

    const unsigned short* Kb = Kg + ((size_t)b * NTOK << 7);
    const unsigned short* Vb = Vg + ((size_t)b * CCH << 12);
    const int* mb = maskb + (size_t)b * NTOK;

    for (int it = 0; it < 64; ++it) {
        const int mk = (kj << 10) + (it << 4);   // 16-key group base

        // mask (keys g*4..+3 of this group)
        const int4 mv = *reinterpret_cast<const int4*>(mb + mk + g * 4);

        // K fragments (A of 16x16x32): lane = K[mk+lr][s*32 + g*8 ..+8]
        bf16x8 kb[4];
        {
            const unsigned short* kp = Kb + ((size_t)(mk + lr) << 7) + g * 8;
            #pragma unroll
            for (int s = 0; s < 4; ++s)
                kb[s] = *reinterpret_cast<const bf16x8*>(kp + s * 32);
        }
        // V fragments (A of 16x16x16): lane = V^T[cf*16+lr][mk + g*4 ..+4]
        bf16x4 vb[8];
        #pragma unroll
        for (int cf = 0; cf < 8; ++cf)
            vb[cf] = *reinterpret_cast<const bf16x4*>(
                Vb + (((size_t)(cf * 16 + lr)) << 12) + mk + g * 4);

        // ---- S^T = mfma(K, Q): lane holds S[key=mk+g*4+i][q=rf*16+lr] ----
        f32x4 sf[2];
        sf[0] = (f32x4){0.f,0.f,0.f,0.f};
        sf[1] = (f32x4){0.f,0.f,0.f,0.f};
        #pragma unroll
        for (int s = 0; s < 4; ++s) {
            sf[0] = __builtin_amdgcn_mfma_f32_16x16x32_bf16(kb[s], qf[0][s], sf[0], 0, 0, 0);
            sf[1] = __builtin_amdgcn_mfma_f32_16x16x32_bf16(kb[s], qf[1][s], sf[1], 0, 0, 0);
        }

        const float mk0 = mv.x ? 1.f : 0.f;
        const float mk1 = mv.y ? 1.f : 0.f;
        const float mk2 = mv.z ? 1.f : 0.f;
        const float mk3 = mv.w ? 1.f : 0.f;

        // ---- softmax + P in registers ----
        bf16x4 pb[2];
        #pragma unroll
        for (int rf = 0; rf < 2; ++rf) {
            float rm = fmaxf(fmaxf(sf[rf][0], sf[rf][1]), fmaxf(sf[rf][2], sf[rf][3]));
            rm = fmaxf(rm, __shfl_xor(rm, 16));
            rm = fmaxf(rm, __shfl_xor(rm, 32));
            if (!__all(rm <= mrun[rf])) {        // exact skip: cr==1 when skipped
                const float mn = fmaxf(mrun[rf], rm);
                const float cr = exp2f(mrun[rf] - mn);
                mrun[rf] = mn;
                lrun[rf] *= cr;
                #pragma unroll
                for (int cf = 0; cf < 8; ++cf) {
                    acc[rf][cf][0] *= cr; acc[rf][cf][1] *= cr;
                    acc[rf][cf][2] *= cr; acc[rf][cf][3] *= cr;
                }
            }
            const float p0 = exp2f(sf[rf][0] - mrun[rf]) * mk0;
            const float p1 = exp2f(sf[rf][1] - mrun[rf]) * mk1;
            const float p2 = exp2f(sf[rf][2] - mrun[rf]) * mk2;
            const float p3 = exp2f(sf[rf][3] - mrun[rf]) * mk3;
            lrun[rf] += (p0 + p1) + (p2 + p3);   // per-lane partial (4 keys)
            const unsigned long long pk =
                (unsigned long long)pack2bf(p0, p1) |
                ((unsigned long long)pack2bf(p2, p3) << 32);
            pb[rf] = __builtin_bit_cast(bf16x4, pk);
        }

        // ---- O^T += mfma16(V, P) ----
        #pragma unroll
        for (int cf = 0; cf < 8; ++cf) {
            acc[0][cf] = mfma16(vb[cf], pb[0], acc[0][cf]);
            acc[1][cf] = mfma16(vb[cf], pb[1], acc[1][cf]);
        }
    }

    // finish deferred row sums across g
    #pragma unroll
    for (int rf = 0; rf < 2; ++rf) {
        lrun[rf] += __shfl_xor(lrun[rf], 16);
        lrun[rf] += __shfl_xor(lrun[rf], 32);
    }

    // ---------------- 4-way tree merge + residual + LayerNorm + transpose ----------
    // publish format: 64 acc floats + m[2] + l[2], stride 69 (conflict-spread)
    if (kj == 1 || kj == 3) {
        float* dst = mrg + (((kj >> 1)) * 64 + l) * 69;
        #pragma unroll
        for (int rf = 0; rf < 2; ++rf)
            #pragma unroll
            for (int cf = 0; cf < 8; ++cf)
                #pragma unroll
                for (int i = 0; i < 4; ++i)
                    dst[rf * 32 + cf * 4 + i] = acc[rf][cf][i];
        dst[64] = mrun[0]; dst[65] = mrun[1];
        dst[66] = lrun[0]; dst[67] = lrun[1];
    }
    {   // stage x tile (c-major, stride 36) — all threads
        const int c = t >> 1, h0 = (t & 1) << 4;
        const float* src = xg + (((size_t)b * CCH + c) << 12) + n0 + h0;
        float* dst = xstg + c * 36 + h0;
        #pragma unroll
        for (int k = 0; k < 16; k += 4)
            *reinterpret_cast<float4*>(dst + k) = *reinterpret_cast<const float4*>(src + k);
    }
    __syncthreads();

    if (kj == 0 || kj == 2) {            // merge partner (kj+1)'s partials
        const float* src = mrg + (((kj >> 1)) * 64 + l) * 69;
        #pragma unroll
        for (int rf = 0; rf < 2; ++rf) {
            const float m1 = src[64 + rf], l1 = src[66 + rf];
            const float mm = fmaxf(mrun[rf], m1);
            const float e0 = exp2f(mrun[rf] - mm);
            const float e1 = exp2f(m1 - mm);
            mrun[rf] = mm;
            lrun[rf] = lrun[rf] * e0 + l1 * e1;
            #pragma unroll
            for (int cf = 0; cf < 8; ++cf)
                #pragma unroll
                for (int i = 0; i < 4; ++i)
                    acc[rf][cf][i] = acc[rf][cf][i] * e0 + src[rf * 32 + cf * 4 + i] * e1;
        }
    }
    __syncthreads();

    if (kj == 2) {                       // publish merged (2,3) into slot 0
        float* dst = mrg + l * 69;
        #pragma unroll
        for (int rf = 0; rf < 2; ++rf)
            #pragma unroll
            for (int cf = 0; cf < 8; ++cf)
                #pragma unroll
                for (int i = 0; i < 4; ++i)
                    dst[rf * 32 + cf * 4 + i] = acc[rf][cf][i];
        dst[64] = mrun[0]; dst[65] = mrun[1];
        dst[66] = lrun[0]; dst[67] = lrun[1];
    }
    __syncthreads();

    if (kj == 0) {                       // final merge + residual + LN
        const float* src = mrg + l * 69;
        float gm[8][4], bt[8][4];
        #pragma unroll
        for (int cf = 0; cf < 8; ++cf)
            #pragma unroll
            for (int i = 0; i < 4; ++i) {
                gm[cf][i] = gamma[cf * 16 + g * 4 + i];
                bt[cf][i] = beta [cf * 16 + g * 4 + i];
            }
        #pragma unroll
        for (int rf = 0; rf < 2; ++rf) {
            const float m1 = src[64 + rf], l1 = src[66 + rf];
            const float mm = fmaxf(mrun[rf], m1);
            const float e0 = exp2f(mrun[rf] - mm);
            const float e1 = exp2f(m1 - mm);
            const float inv = 1.f / (lrun[rf] * e0 + l1 * e1);
            const int nloc = rf * 16 + lr;
            float sum = 0.f, sq = 0.f;
            #pragma unroll
            for (int cf = 0; cf < 8; ++cf)
                #pragma unroll
                for (int i = 0; i < 4; ++i) {
                    const float o = acc[rf][cf][i] * e0 + src[rf * 32 + cf * 4 + i] * e1;
                    const float v = o * inv + xstg[(cf * 16 + g * 4 + i) * 36 + nloc];
                    acc[rf][cf][i] = v; sum += v; sq += v * v;
                }
            sum += __shfl_xor(sum, 16); sq += __shfl_xor(sq, 16);
            sum += __shfl_xor(sum, 32); sq += __shfl_xor(sq, 32);
            const float mean = sum * (1.f / 128.f);
            const float var  = sq * (1.f / 128.f) - mean * mean;
            const float rstd = rsqrtf(var + 1e-5f);
            #pragma unroll
            for (int cf = 0; cf < 8; ++cf)
                #pragma unroll
                for (int i = 0; i < 4; ++i)
                    xstg[(cf * 16 + g * 4 + i) * 36 + nloc] =
                        (acc[rf][cf][i] - mean) * rstd * gm[cf][i] + bt[cf][i];
        }
    }
    __syncthreads();

    {   // coalesced transposed store — all threads
        const int c = t >> 1, h0 = (t & 1) << 4;
        float* dst = out + (((size_t)b * CCH + c) << 12) + n0 + h0;
        const float* srcl = xstg + c * 36 + h0;
        #pragma unroll
        for (int k = 0; k < 16; k += 4)
            *reinterpret_cast<float4*>(dst + k) = *reinterpret_cast<const float4*>(srcl + k);
    }
}

extern "C" void kernel_launch(void* const* d_in, const int* in_sizes, int n_in,
                              void* d_out, int out_size, void* d_ws, size_t ws_size,
                              hipStream_t stream) {
    const float* prompt = (const float*)d_in[0];
    const float* x      = (const float*)d_in[1];
    const float* Wq     = (const float*)d_in[2];
    const float* bq     = (const float*)d_in[3];
    const float* Wk     = (const float*)d_in[4];
    const float* bk     = (const float*)d_in[5];
    const float* Wv     = (const float*)d_in[6];
    const float* bv     = (const float*)d_in[7];
    const float* gamma  = (const float*)d_in[8];
    const float* beta   = (const float*)d_in[9];
    const int*   maskb  = (const int*)d_in[10];
    float* out = (float*)d_out;

    const size_t M = (size_t)4 * NTOK * CCH;
    unsigned short* Qw = (unsigned short*)d_ws;
    unsigned short* Kw = Qw + M;
    unsigned short* Vw = Kw + M;

    (void)hipFuncSetAttribute((const void*)qkv_kernel,
                              hipFuncAttributeMaxDynamicSharedMemorySize, 65536);

    qkv_kernel<<<256, 256, 65536, stream>>>(prompt, x, Wq, bq, Wk, bk, Wv, bv, Qw, Kw, Vw);
    attn_ln_kernel<<<512, 256, 0, stream>>>(Qw, Kw, Vw, maskb, x, gamma, beta, out);
}